// Round 6
// baseline (294.820 us; speedup 1.0000x reference)
//
#include <hip/hip_runtime.h>
#include <hip/hip_cooperative_groups.h>

namespace cg = cooperative_groups;

#define B_ 32
#define C_ 64
#define H_ 128
#define W_ 128
#define HW_ (H_*W_)
#define CHW_ (C_*HW_)

typedef float f4 __attribute__((ext_vector_type(4)));

// ===========================================================================
// Cooperative mega-kernel: 1024 blocks x 256 thr, 4 blocks/CU.
// Phase A: even blocks -> k1 reduction tile; odd blocks < 128 -> zpos.
// grid.sync() replaces the two kernel-boundary drains.
// Phase C: tiles 2*blk and 2*blk+1 (same batch, adjacent rows -> map rows
// L2-hit on 2nd tile; router/weights computed once). xva[8]-only prefetch
// keeps VGPR ~100 < 128 so 4 blocks/CU residency is guaranteed.
// ===========================================================================
__global__ __launch_bounds__(256, 4) void mega(
    const float* __restrict__ x,
    float* __restrict__ avgmap, float* __restrict__ maxmap,
    float* __restrict__ partial, float* __restrict__ zpos,
    const float* __restrict__ dw0, const float* __restrict__ dw1,
    const float* __restrict__ dw2,
    const float* __restrict__ pw0w, const float* __restrict__ pw0b,
    const float* __restrict__ pw1w, const float* __restrict__ pw1b,
    const float* __restrict__ pw2w, const float* __restrict__ pw2b,
    const float* __restrict__ rw1, const float* __restrict__ rb1,
    const float* __restrict__ rw2, const float* __restrict__ rb2,
    const float* __restrict__ t_raw,
    float* __restrict__ y, float* __restrict__ sa_out)
{
    __shared__ float sA[14][140];
    __shared__ float sM[14][140];
    __shared__ float wA0[9], wM0[9];
    __shared__ float wA1[49], wM1[49], wA2[49], wM2[49];
    __shared__ __align__(16) float ssa[256];
    __shared__ float sRW[4];
    __shared__ float wa[4], wm[4];

    int blk = blockIdx.x;                  // 0..1023
    int tix = threadIdx.x;

    // ======================= Phase A =====================================
    if ((blk & 1) == 0) {
        int tile = blk >> 1;               // 0..511
        int t = tile * 256 + tix;
        int base = t * 4;
        int b = base >> 14;
        int q = base & (HW_ - 1);
        const float4* xp = (const float4*)(x + (size_t)b * CHW_ + q);
        float4 v = xp[0];
        float4 s = v, m = v;
        #pragma unroll 8
        for (int c = 1; c < C_; ++c) {
            float4 u = xp[c * (HW_ / 4)];
            s.x += u.x; s.y += u.y; s.z += u.z; s.w += u.w;
            m.x = fmaxf(m.x, u.x); m.y = fmaxf(m.y, u.y);
            m.z = fmaxf(m.z, u.z); m.w = fmaxf(m.w, u.w);
        }
        const float inv = 1.0f / C_;
        float4 a = make_float4(s.x * inv, s.y * inv, s.z * inv, s.w * inv);
        ((float4*)avgmap)[t] = a;
        ((float4*)maxmap)[t] = m;

        float la = a.x + a.y + a.z + a.w;
        float lm = m.x + m.y + m.z + m.w;
        #pragma unroll
        for (int o = 32; o > 0; o >>= 1) {
            la += __shfl_down(la, o);
            lm += __shfl_down(lm, o);
        }
        int lane = tix & 63, wid = tix >> 6;
        if (lane == 0) { wa[wid] = la; wm[wid] = lm; }
        __syncthreads();
        if (tix == 0) {
            partial[2 * tile]     = wa[0] + wa[1] + wa[2] + wa[3];
            partial[2 * tile + 1] = wm[0] + wm[1] + wm[2] + wm[3];
        }
    } else if (blk < 128) {
        int p = (blk >> 1) * 256 + tix;    // 64 odd blocks cover HW
        int gy = p >> 7, gx = p & 127;
        const float sc = 2.0f / 127.0f;
        float z0 = pw0b[0], z1 = pw1b[0], z2 = pw2b[0];
        float px0 = pw0w[2], py0 = pw0w[3];
        float px1 = pw1w[2], py1 = pw1w[3];
        float px2 = pw2w[2], py2 = pw2w[3];

        #pragma unroll
        for (int ky = 0; ky < 3; ++ky)
        #pragma unroll
        for (int kx = 0; kx < 3; ++kx) {
            int iy = gy + ky - 1, ix = gx + kx - 1;
            bool ok = ((unsigned)iy < H_) && ((unsigned)ix < W_);
            float xv = ok ? ix * sc - 1.0f : 0.0f;
            float yv = ok ? iy * sc - 1.0f : 0.0f;
            int t = ky * 3 + kx;
            z0 += px0 * dw0[18 + t] * xv + py0 * dw0[27 + t] * yv;
        }
        #pragma unroll
        for (int ky = 0; ky < 7; ++ky)
        #pragma unroll
        for (int kx = 0; kx < 7; ++kx) {
            int iy = gy + ky - 3, ix = gx + kx - 3;
            bool ok = ((unsigned)iy < H_) && ((unsigned)ix < W_);
            float xv = ok ? ix * sc - 1.0f : 0.0f;
            float yv = ok ? iy * sc - 1.0f : 0.0f;
            int t = ky * 7 + kx;
            z1 += px1 * dw1[98 + t] * xv + py1 * dw1[147 + t] * yv;
        }
        #pragma unroll
        for (int ky = 0; ky < 7; ++ky)
        #pragma unroll
        for (int kx = 0; kx < 7; ++kx) {
            int iy = gy + (ky - 3) * 2, ix = gx + (kx - 3) * 2;
            bool ok = ((unsigned)iy < H_) && ((unsigned)ix < W_);
            float xv = ok ? ix * sc - 1.0f : 0.0f;
            float yv = ok ? iy * sc - 1.0f : 0.0f;
            int t = ky * 7 + kx;
            z2 += px2 * dw2[98 + t] * xv + py2 * dw2[147 + t] * yv;
        }
        zpos[p]           = z0;
        zpos[HW_ + p]     = z1;
        zpos[2 * HW_ + p] = z2;
    }

    cg::this_grid().sync();

    // ======================= Phase C =====================================
    #pragma unroll 1
    for (int t2 = 0; t2 < 2; ++t2) {
        int tile = blk * 2 + t2;           // same batch both iters
        int b  = tile >> 6;
        int y0 = (tile & 63) * 2;

        __syncthreads();                   // LDS WAR guard between tiles

        const float* am = avgmap + (size_t)b * HW_;
        const float* mm = maxmap + (size_t)b * HW_;

        // stage 14 rows x 128 cols of each map, rows y0-6 .. y0+7
        for (int idx = tix; idx < 14 * 32; idx += 256) {
            int r = idx >> 5, c4 = idx & 31;
            int gy = y0 - 6 + r;
            bool ok = (unsigned)gy < H_;
            float4 av = ok ? ((const float4*)(am + gy * W_))[c4]
                           : make_float4(0.f, 0.f, 0.f, 0.f);
            float4 mv = ok ? ((const float4*)(mm + gy * W_))[c4]
                           : make_float4(0.f, 0.f, 0.f, 0.f);
            float* pa = &sA[r][6 + c4 * 4];
            float* pm = &sM[r][6 + c4 * 4];
            pa[0] = av.x; pa[1] = av.y; pa[2] = av.z; pa[3] = av.w;
            pm[0] = mv.x; pm[1] = mv.y; pm[2] = mv.z; pm[3] = mv.w;
        }
        for (int idx = tix; idx < 14 * 12; idx += 256) {
            int r = idx / 12, c = idx % 12;
            int cc = (c < 6) ? c : (134 + c - 6);
            sA[r][cc] = 0.0f;
            sM[r][cc] = 0.0f;
        }
        if (t2 == 0) {
            if (tix < 9)  { wA0[tix] = pw0w[0] * dw0[tix];
                            wM0[tix] = pw0w[1] * dw0[9 + tix]; }
            if (tix < 49) { wA1[tix] = pw1w[0] * dw1[tix];
                            wM1[tix] = pw1w[1] * dw1[49 + tix];
                            wA2[tix] = pw2w[0] * dw2[tix];
                            wM2[tix] = pw2w[1] * dw2[49 + tix]; }
            if (tix == 0) {
                float s0 = 0.0f, s1 = 0.0f;
                #pragma unroll
                for (int i = 0; i < 16; ++i) {
                    s0 += partial[2 * (b * 16 + i)];
                    s1 += partial[2 * (b * 16 + i) + 1];
                }
                float p0 = s0 * (1.0f / HW_);
                float p1 = s1 * (1.0f / HW_);
                float hid[8];
                #pragma unroll
                for (int j = 0; j < 8; ++j)
                    hid[j] = fmaxf(0.0f, rb1[j] + rw1[j * 4] * p0 + rw1[j * 4 + 1] * p1);
                float lg[3];
                #pragma unroll
                for (int i = 0; i < 3; ++i) {
                    float acc = rb2[i];
                    #pragma unroll
                    for (int j = 0; j < 8; ++j) acc += hid[j] * rw2[i * 8 + j];
                    lg[i] = acc;
                }
                float mx = fmaxf(lg[0], fmaxf(lg[1], lg[2]));
                float e0 = expf(lg[0] - mx), e1 = expf(lg[1] - mx), e2 = expf(lg[2] - mx);
                float inv = 1.0f / (e0 + e1 + e2);
                sRW[0] = e0 * inv;
                sRW[1] = e1 * inv;
                sRW[2] = e2 * inv;
                sRW[3] = 1.0f / (log1pf(expf(t_raw[0])) + 1e-6f);
            }
        }

        int ly = tix >> 7;
        int lx = tix & 127;
        int gy = y0 + ly;
        int pidx = gy * W_ + lx;

        // zpos issued early; consumed only after the conv
        float z0 = zpos[pidx];
        float z1 = zpos[HW_ + pidx];
        float z2 = zpos[2 * HW_ + pidx];

        __syncthreads();                   // maps staged

        int wid  = tix >> 6;
        int lane = tix & 63;
        const float* xt = x + (size_t)b * CHW_ + y0 * W_;
        float*       yt = y + (size_t)b * CHW_ + y0 * W_;

        // prefetch first 8 channel-groups only (32 VGPR) — keeps VGPR < 128
        f4 xva[8];
        #pragma unroll
        for (int k = 0; k < 8; ++k)
            xva[k] = *((const f4*)(xt + (wid + k * 4) * HW_) + lane);

        float c0 = 0.0f, c1 = 0.0f, c2 = 0.0f;
        #pragma unroll
        for (int ky = 0; ky < 7; ++ky) {
            const float* ra = &sA[ly + 3 + ky][lx + 3];
            const float* rm = &sM[ly + 3 + ky][lx + 3];
            float av[7], mv[7];
            #pragma unroll
            for (int j = 0; j < 7; ++j) { av[j] = ra[j]; mv[j] = rm[j]; }
            #pragma unroll
            for (int j = 0; j < 7; ++j) {
                int t = ky * 7 + j;
                c1 += wA1[t] * av[j] + wM1[t] * mv[j];
            }
            if (ky >= 2 && ky <= 4) {
                #pragma unroll
                for (int j = 2; j <= 4; ++j) {
                    int t = (ky - 2) * 3 + (j - 2);
                    c0 += wA0[t] * av[j] + wM0[t] * mv[j];
                }
            }
        }
        #pragma unroll
        for (int ky = 0; ky < 7; ++ky) {
            const float* ra = &sA[ly + 2 * ky][lx];
            const float* rm = &sM[ly + 2 * ky][lx];
            #pragma unroll
            for (int kx = 0; kx < 7; ++kx) {
                int t = ky * 7 + kx;
                c2 += wA2[t] * ra[2 * kx] + wM2[t] * rm[2 * kx];
            }
        }

        float wl = sRW[0] * (z0 + c0) + sRW[1] * (z1 + c1) + sRW[2] * (z2 + c2);
        float s = 1.0f / (1.0f + expf(-wl * sRW[3]));
        ssa[tix] = s;
        __builtin_nontemporal_store(s, &sa_out[(size_t)b * HW_ + pidx]);
        __syncthreads();

        f4 sv = ((const f4*)ssa)[lane];
        #pragma unroll
        for (int k = 0; k < 8; ++k) {
            f4 r = xva[k] * sv;
            __builtin_nontemporal_store(r, (f4*)(yt + (wid + k * 4) * HW_) + lane);
        }
        #pragma unroll
        for (int k = 8; k < 16; ++k) {
            f4 v = *((const f4*)(xt + (wid + k * 4) * HW_) + lane);
            f4 r = v * sv;
            __builtin_nontemporal_store(r, (f4*)(yt + (wid + k * 4) * HW_) + lane);
        }
    }
}

// ===========================================================================
// Fallback path — verbatim round-4 kernels (passed at 293.7 us).
// ===========================================================================
__global__ __launch_bounds__(256) void k0_zpos(
    const float* __restrict__ dw0, const float* __restrict__ dw1,
    const float* __restrict__ dw2,
    const float* __restrict__ pw0w, const float* __restrict__ pw0b,
    const float* __restrict__ pw1w, const float* __restrict__ pw1b,
    const float* __restrict__ pw2w, const float* __restrict__ pw2b,
    float* __restrict__ zpos)
{
    int p = blockIdx.x * 256 + threadIdx.x;
    int gy = p >> 7, gx = p & 127;
    const float sc = 2.0f / 127.0f;
    float z0 = pw0b[0], z1 = pw1b[0], z2 = pw2b[0];
    float px0 = pw0w[2], py0 = pw0w[3];
    float px1 = pw1w[2], py1 = pw1w[3];
    float px2 = pw2w[2], py2 = pw2w[3];

    #pragma unroll
    for (int ky = 0; ky < 3; ++ky)
    #pragma unroll
    for (int kx = 0; kx < 3; ++kx) {
        int iy = gy + ky - 1, ix = gx + kx - 1;
        bool ok = ((unsigned)iy < H_) && ((unsigned)ix < W_);
        float xv = ok ? ix * sc - 1.0f : 0.0f;
        float yv = ok ? iy * sc - 1.0f : 0.0f;
        int t = ky * 3 + kx;
        z0 += px0 * dw0[18 + t] * xv + py0 * dw0[27 + t] * yv;
    }
    #pragma unroll
    for (int ky = 0; ky < 7; ++ky)
    #pragma unroll
    for (int kx = 0; kx < 7; ++kx) {
        int iy = gy + ky - 3, ix = gx + kx - 3;
        bool ok = ((unsigned)iy < H_) && ((unsigned)ix < W_);
        float xv = ok ? ix * sc - 1.0f : 0.0f;
        float yv = ok ? iy * sc - 1.0f : 0.0f;
        int t = ky * 7 + kx;
        z1 += px1 * dw1[98 + t] * xv + py1 * dw1[147 + t] * yv;
    }
    #pragma unroll
    for (int ky = 0; ky < 7; ++ky)
    #pragma unroll
    for (int kx = 0; kx < 7; ++kx) {
        int iy = gy + (ky - 3) * 2, ix = gx + (kx - 3) * 2;
        bool ok = ((unsigned)iy < H_) && ((unsigned)ix < W_);
        float xv = ok ? ix * sc - 1.0f : 0.0f;
        float yv = ok ? iy * sc - 1.0f : 0.0f;
        int t = ky * 7 + kx;
        z2 += px2 * dw2[98 + t] * xv + py2 * dw2[147 + t] * yv;
    }
    zpos[p]           = z0;
    zpos[HW_ + p]     = z1;
    zpos[2 * HW_ + p] = z2;
}

__global__ __launch_bounds__(256) void k1_reduce(
    const float* __restrict__ x, float* __restrict__ avgmap,
    float* __restrict__ maxmap, float* __restrict__ partial)
{
    int t = blockIdx.x * 256 + threadIdx.x;
    int base = t * 4;
    int b = base >> 14;
    int q = base & (HW_ - 1);
    const float4* xp = (const float4*)(x + (size_t)b * CHW_ + q);
    float4 v = xp[0];
    float4 s = v, m = v;
    #pragma unroll 8
    for (int c = 1; c < C_; ++c) {
        float4 u = xp[c * (HW_ / 4)];
        s.x += u.x; s.y += u.y; s.z += u.z; s.w += u.w;
        m.x = fmaxf(m.x, u.x); m.y = fmaxf(m.y, u.y);
        m.z = fmaxf(m.z, u.z); m.w = fmaxf(m.w, u.w);
    }
    const float inv = 1.0f / C_;
    float4 a = make_float4(s.x * inv, s.y * inv, s.z * inv, s.w * inv);
    ((float4*)avgmap)[t] = a;
    ((float4*)maxmap)[t] = m;

    float la = a.x + a.y + a.z + a.w;
    float lm = m.x + m.y + m.z + m.w;
    #pragma unroll
    for (int o = 32; o > 0; o >>= 1) {
        la += __shfl_down(la, o);
        lm += __shfl_down(lm, o);
    }
    __shared__ float wa[4], wm[4];
    int lane = threadIdx.x & 63, wid = threadIdx.x >> 6;
    if (lane == 0) { wa[wid] = la; wm[wid] = lm; }
    __syncthreads();
    if (threadIdx.x == 0) {
        partial[2 * blockIdx.x]     = wa[0] + wa[1] + wa[2] + wa[3];
        partial[2 * blockIdx.x + 1] = wm[0] + wm[1] + wm[2] + wm[3];
    }
}

__global__ __launch_bounds__(256) void k34_fused(
    const float* __restrict__ x,
    const float* __restrict__ avgmap, const float* __restrict__ maxmap,
    const float* __restrict__ dw0, const float* __restrict__ dw1,
    const float* __restrict__ dw2,
    const float* __restrict__ pw0w, const float* __restrict__ pw1w,
    const float* __restrict__ pw2w,
    const float* __restrict__ zpos,
    const float* __restrict__ partial,
    const float* __restrict__ rw1, const float* __restrict__ rb1,
    const float* __restrict__ rw2, const float* __restrict__ rb2,
    const float* __restrict__ t_raw,
    float* __restrict__ y, float* __restrict__ sa_out)
{
    __shared__ float sA[14][140];
    __shared__ float sM[14][140];
    __shared__ float wA0[9], wM0[9];
    __shared__ float wA1[49], wM1[49], wA2[49], wM2[49];
    __shared__ __align__(16) float ssa[256];
    __shared__ float sRW[4];

    int b  = blockIdx.y;
    int y0 = blockIdx.x * 2;
    int tix = threadIdx.x;
    const float* am = avgmap + (size_t)b * HW_;
    const float* mm = maxmap + (size_t)b * HW_;

    for (int idx = tix; idx < 14 * 32; idx += 256) {
        int r = idx >> 5, c4 = idx & 31;
        int gy = y0 - 6 + r;
        bool ok = (unsigned)gy < H_;
        float4 av = ok ? ((const float4*)(am + gy * W_))[c4]
                       : make_float4(0.f, 0.f, 0.f, 0.f);
        float4 mv = ok ? ((const float4*)(mm + gy * W_))[c4]
                       : make_float4(0.f, 0.f, 0.f, 0.f);
        float* pa = &sA[r][6 + c4 * 4];
        float* pm = &sM[r][6 + c4 * 4];
        pa[0] = av.x; pa[1] = av.y; pa[2] = av.z; pa[3] = av.w;
        pm[0] = mv.x; pm[1] = mv.y; pm[2] = mv.z; pm[3] = mv.w;
    }
    for (int idx = tix; idx < 14 * 12; idx += 256) {
        int r = idx / 12, c = idx % 12;
        int cc = (c < 6) ? c : (134 + c - 6);
        sA[r][cc] = 0.0f;
        sM[r][cc] = 0.0f;
    }
    if (tix < 9)  { wA0[tix] = pw0w[0] * dw0[tix];
                    wM0[tix] = pw0w[1] * dw0[9 + tix]; }
    if (tix < 49) { wA1[tix] = pw1w[0] * dw1[tix];
                    wM1[tix] = pw1w[1] * dw1[49 + tix];
                    wA2[tix] = pw2w[0] * dw2[tix];
                    wM2[tix] = pw2w[1] * dw2[49 + tix]; }
    if (tix == 0) {
        float s0 = 0.0f, s1 = 0.0f;
        #pragma unroll
        for (int i = 0; i < 16; ++i) {
            s0 += partial[2 * (b * 16 + i)];
            s1 += partial[2 * (b * 16 + i) + 1];
        }
        float p0 = s0 * (1.0f / HW_);
        float p1 = s1 * (1.0f / HW_);
        float hid[8];
        #pragma unroll
        for (int j = 0; j < 8; ++j)
            hid[j] = fmaxf(0.0f, rb1[j] + rw1[j * 4] * p0 + rw1[j * 4 + 1] * p1);
        float lg[3];
        #pragma unroll
        for (int i = 0; i < 3; ++i) {
            float acc = rb2[i];
            #pragma unroll
            for (int j = 0; j < 8; ++j) acc += hid[j] * rw2[i * 8 + j];
            lg[i] = acc;
        }
        float mx = fmaxf(lg[0], fmaxf(lg[1], lg[2]));
        float e0 = expf(lg[0] - mx), e1 = expf(lg[1] - mx), e2 = expf(lg[2] - mx);
        float inv = 1.0f / (e0 + e1 + e2);
        sRW[0] = e0 * inv;
        sRW[1] = e1 * inv;
        sRW[2] = e2 * inv;
        sRW[3] = 1.0f / (log1pf(expf(t_raw[0])) + 1e-6f);
    }

    int ly = tix >> 7;
    int lx = tix & 127;
    int gy = y0 + ly;
    int pidx = gy * W_ + lx;

    float z0 = zpos[pidx];
    float z1 = zpos[HW_ + pidx];
    float z2 = zpos[2 * HW_ + pidx];

    __syncthreads();

    int wid  = tix >> 6;
    int lane = tix & 63;
    const float* xt = x + (size_t)b * CHW_ + y0 * W_;
    float*       yt = y + (size_t)b * CHW_ + y0 * W_;
    f4 xv[16];
    #pragma unroll
    for (int k = 0; k < 16; ++k)
        xv[k] = *((const f4*)(xt + (wid + k * 4) * HW_) + lane);

    float c0 = 0.0f, c1 = 0.0f, c2 = 0.0f;
    #pragma unroll
    for (int ky = 0; ky < 7; ++ky) {
        const float* ra = &sA[ly + 3 + ky][lx + 3];
        const float* rm = &sM[ly + 3 + ky][lx + 3];
        float av[7], mv[7];
        #pragma unroll
        for (int j = 0; j < 7; ++j) { av[j] = ra[j]; mv[j] = rm[j]; }
        #pragma unroll
        for (int j = 0; j < 7; ++j) {
            int t = ky * 7 + j;
            c1 += wA1[t] * av[j] + wM1[t] * mv[j];
        }
        if (ky >= 2 && ky <= 4) {
            #pragma unroll
            for (int j = 2; j <= 4; ++j) {
                int t = (ky - 2) * 3 + (j - 2);
                c0 += wA0[t] * av[j] + wM0[t] * mv[j];
            }
        }
    }
    #pragma unroll
    for (int ky = 0; ky < 7; ++ky) {
        const float* ra = &sA[ly + 2 * ky][lx];
        const float* rm = &sM[ly + 2 * ky][lx];
        #pragma unroll
        for (int kx = 0; kx < 7; ++kx) {
            int t = ky * 7 + kx;
            c2 += wA2[t] * ra[2 * kx] + wM2[t] * rm[2 * kx];
        }
    }

    float wl = sRW[0] * (z0 + c0) + sRW[1] * (z1 + c1) + sRW[2] * (z2 + c2);
    float s = 1.0f / (1.0f + expf(-wl * sRW[3]));
    ssa[tix] = s;
    __builtin_nontemporal_store(s, &sa_out[(size_t)b * HW_ + pidx]);
    __syncthreads();

    f4 sv = ((const f4*)ssa)[lane];
    #pragma unroll
    for (int k = 0; k < 16; ++k) {
        f4 r = xv[k] * sv;
        __builtin_nontemporal_store(r, (f4*)(yt + (wid + k * 4) * HW_) + lane);
    }
}

extern "C" void kernel_launch(void* const* d_in, const int* in_sizes, int n_in,
                              void* d_out, int out_size, void* d_ws, size_t ws_size,
                              hipStream_t stream)
{
    const float* x     = (const float*)d_in[0];
    const float* dw0   = (const float*)d_in[1];
    const float* dw1   = (const float*)d_in[2];
    const float* dw2   = (const float*)d_in[3];
    const float* pw0w  = (const float*)d_in[4];
    const float* pw0b  = (const float*)d_in[5];
    const float* pw1w  = (const float*)d_in[6];
    const float* pw1b  = (const float*)d_in[7];
    const float* pw2w  = (const float*)d_in[8];
    const float* pw2b  = (const float*)d_in[9];
    const float* rw1   = (const float*)d_in[10];
    const float* rb1   = (const float*)d_in[11];
    const float* rw2   = (const float*)d_in[12];
    const float* rb2   = (const float*)d_in[13];
    const float* t_raw = (const float*)d_in[14];

    float* ws      = (float*)d_ws;
    float* avgmap  = ws;                       // 524288 floats
    float* maxmap  = ws + 524288;              // 524288 floats
    float* partial = ws + 1048576;             // 1024 floats
    float* zpos    = ws + 1049600;             // 3*16384 floats

    float* Y  = (float*)d_out;
    float* sa = Y + (size_t)B_ * CHW_;         // 524288 floats

    // Gate: only attempt cooperative launch if 4 blocks/CU are resident
    // (1024 blocks on 256 CUs). Host-side query, legal under graph capture.
    static int use_coop = -1;
    if (use_coop < 0) {
        int nb = 0;
        hipError_t e = hipOccupancyMaxActiveBlocksPerMultiprocessor(
            &nb, (const void*)mega, 256, 0);
        use_coop = (e == hipSuccess && nb >= 4) ? 1 : 0;
    }

    if (use_coop) {
        void* args[] = {
            (void*)&x, (void*)&avgmap, (void*)&maxmap, (void*)&partial,
            (void*)&zpos,
            (void*)&dw0, (void*)&dw1, (void*)&dw2,
            (void*)&pw0w, (void*)&pw0b, (void*)&pw1w, (void*)&pw1b,
            (void*)&pw2w, (void*)&pw2b,
            (void*)&rw1, (void*)&rb1, (void*)&rw2, (void*)&rb2,
            (void*)&t_raw, (void*)&Y, (void*)&sa
        };
        hipError_t e = hipLaunchCooperativeKernel(
            (const void*)mega, dim3(1024), dim3(256), args, 0, stream);
        if (e == hipSuccess) return;
        use_coop = 0;                      // fall through to safe path
    }

    // Fallback: round-4 three-kernel path (verified passing).
    k1_reduce<<<B_ * HW_ / 4 / 256, 256, 0, stream>>>(x, avgmap, maxmap, partial);
    k0_zpos<<<HW_ / 256, 256, 0, stream>>>(
        dw0, dw1, dw2, pw0w, pw0b, pw1w, pw1b, pw2w, pw2b, zpos);

    dim3 g34(H_ / 2, B_);
    k34_fused<<<g34, 256, 0, stream>>>(
        x, avgmap, maxmap, dw0, dw1, dw2,
        pw0w, pw1w, pw2w, zpos,
        partial, rw1, rb1, rw2, rb2, t_raw, Y, sa);
}